// Round 1
// baseline (303.474 us; speedup 1.0000x reference)
//
#include <hip/hip_runtime.h>

#define N_ENTITY 100000
#define D 128
#define HID 256
#define N_REL 48
#define N_BASES 8
#define N_EDGES 1000000
#define NPOS 1024   // 32*32 output positions

// ws layout in 4-byte elements
#define OFF_MAP   0                        // int[N_ENTITY]
#define OFF_CNT   100032                   // int[16] (counter at [0])
#define OFF_DEG   100048                   // int[NPOS*N_REL]
#define OFF_ELIST 149200                   // int[N_EDGES]
#define OFF_ACC   1149200                  // float[NPOS*N_BASES*D]
#define OFF_ENT   2197776                  // float[NPOS*HID]
// total = 2459920 elems ~ 9.84 MB

// Sentinel for "not a target": memset 0x7F -> 0x7F7F7F7F = 2139062143
#define SENTINEL 0x7F7F7F7F

__global__ void k_register(const int* __restrict__ eids, int* __restrict__ map) {
    int pos = threadIdx.x;            // blockDim = 1024
    int e = eids[pos];
    atomicMin(&map[e], pos);          // owner slot = min position
}

__global__ void k_scan(const int* __restrict__ dst, const int* __restrict__ etype,
                       const int* __restrict__ map, int* __restrict__ deg,
                       int* __restrict__ elist, int* __restrict__ cnt) {
    int e = blockIdx.x * blockDim.x + threadIdx.x;
    if (e >= N_EDGES) return;
    int u = map[dst[e]];
    if (u < NPOS) {
        atomicAdd(&deg[u * N_REL + etype[e]], 1);
        int idx = atomicAdd(cnt, 1);
        elist[idx] = e;
    }
}

// one wave per matching edge, grid-stride over the compacted list
__global__ void k_acc(const int* __restrict__ src, const int* __restrict__ dst,
                      const int* __restrict__ etype, const int* __restrict__ map,
                      const int* __restrict__ deg, const int* __restrict__ elist,
                      const int* __restrict__ cnt, const float* __restrict__ x,
                      const float* __restrict__ comp, float* __restrict__ acc8) {
    int n = cnt[0];
    int gtid = blockIdx.x * blockDim.x + threadIdx.x;
    int wave = gtid >> 6;
    int lane = threadIdx.x & 63;
    int nwaves = (gridDim.x * blockDim.x) >> 6;
    for (int i = wave; i < n; i += nwaves) {
        int e = elist[i];
        int t = etype[e];
        int u = map[dst[e]];
        float norm = 1.0f / fmaxf((float)deg[u * N_REL + t], 1.0f);
        float coeff[N_BASES];
        #pragma unroll
        for (int k = 0; k < N_BASES; k++) coeff[k] = comp[t * N_BASES + k] * norm;
        const float* xs = x + (size_t)src[e] * D;
        float xv0 = xs[lane];
        float xv1 = xs[lane + 64];
        float* accu = acc8 + (size_t)u * (N_BASES * D);
        #pragma unroll
        for (int k = 0; k < N_BASES; k++) {
            atomicAdd(&accu[k * D + lane],      coeff[k] * xv0);
            atomicAdd(&accu[k * D + lane + 64], coeff[k] * xv1);
        }
    }
}

__global__ __launch_bounds__(256) void k_fused(
        const int* __restrict__ eids, const int* __restrict__ map,
        const float* __restrict__ x, const float* __restrict__ bases,
        const float* __restrict__ root, const float* __restrict__ bias,
        const float* __restrict__ w1, const float* __restrict__ b1,
        const float* __restrict__ w2, const float* __restrict__ b2,
        const float* __restrict__ wp, const float* __restrict__ bp,
        const float* __restrict__ acc8, float* __restrict__ ent) {
    int u = blockIdx.x;
    int ename = eids[u];
    if (map[ename] != u) return;      // not the owner slot for this entity
    __shared__ float xs[D];
    __shared__ float accs[N_BASES * D];
    __shared__ float hs[D];
    __shared__ float t1[D / 2];
    __shared__ float h2[D];
    int tid = threadIdx.x;
    const float* xrow = x + (size_t)ename * D;
    if (tid < D) xs[tid] = xrow[tid];
    for (int i = tid; i < N_BASES * D; i += 256)
        accs[i] = acc8[(size_t)u * (N_BASES * D) + i];
    __syncthreads();
    // RGCN: h = x@root + bias + sum_k acc_k @ B_k + x (residual)
    if (tid < D) {
        float s = bias[tid];
        for (int i = 0; i < D; i++) {
            s += xs[i] * root[i * D + tid];
            #pragma unroll
            for (int k = 0; k < N_BASES; k++)
                s += accs[k * D + i] * bases[(k * D + i) * D + tid];
        }
        hs[tid] = s + xs[tid];
    }
    __syncthreads();
    // t1 = relu(h @ w1 + b1)
    if (tid < D / 2) {
        float s = b1[tid];
        for (int i = 0; i < D; i++) s += hs[i] * w1[i * (D / 2) + tid];
        t1[tid] = fmaxf(s, 0.0f);
    }
    __syncthreads();
    // h2 = t1 @ w2 + b2 + h
    if (tid < D) {
        float s = b2[tid] + hs[tid];
        for (int i = 0; i < D / 2; i++) s += t1[i] * w2[i * D + tid];
        h2[tid] = s;
    }
    __syncthreads();
    // ent = h2 @ wp + bp   (256 outputs, one per thread)
    {
        float s = bp[tid];
        for (int i = 0; i < D; i++) s += h2[i] * wp[i * HID + tid];
        ent[(size_t)u * HID + tid] = s;
    }
}

__global__ void k_gather(const int* __restrict__ eids, const int* __restrict__ map,
                         const float* __restrict__ ent, float* __restrict__ out) {
    int pos = blockIdx.x;             // 1024 blocks of HID threads
    int u = map[eids[pos]];
    out[pos * HID + threadIdx.x] = ent[(size_t)u * HID + threadIdx.x];
}

extern "C" void kernel_launch(void* const* d_in, const int* in_sizes, int n_in,
                              void* d_out, int out_size, void* d_ws, size_t ws_size,
                              hipStream_t stream) {
    const float* x     = (const float*)d_in[0];
    const float* bases = (const float*)d_in[1];
    const float* comp  = (const float*)d_in[2];
    const float* root  = (const float*)d_in[3];
    const float* bias  = (const float*)d_in[4];
    const float* w1    = (const float*)d_in[5];
    const float* b1    = (const float*)d_in[6];
    const float* w2    = (const float*)d_in[7];
    const float* b2    = (const float*)d_in[8];
    const float* wp    = (const float*)d_in[9];
    const float* bp    = (const float*)d_in[10];
    const int* eidx    = (const int*)d_in[11];
    const int* srcp    = eidx;
    const int* dstp    = eidx + N_EDGES;
    const int* etype   = (const int*)d_in[12];
    const int* eids    = (const int*)d_in[13];
    float* out = (float*)d_out;

    int*   ws    = (int*)d_ws;
    int*   map   = ws + OFF_MAP;
    int*   cnt   = ws + OFF_CNT;
    int*   deg   = ws + OFF_DEG;
    int*   elist = ws + OFF_ELIST;
    float* acc8  = (float*)(ws + OFF_ACC);
    float* ent   = (float*)(ws + OFF_ENT);

    // init: map -> sentinel, cnt+deg -> 0, acc8 -> 0
    hipMemsetAsync(map, 0x7F, (size_t)N_ENTITY * sizeof(int), stream);
    hipMemsetAsync(cnt, 0, (size_t)(16 + NPOS * N_REL) * sizeof(int), stream);
    hipMemsetAsync(acc8, 0, (size_t)(NPOS * N_BASES * D) * sizeof(float), stream);

    k_register<<<1, NPOS, 0, stream>>>(eids, map);
    k_scan<<<(N_EDGES + 255) / 256, 256, 0, stream>>>(dstp, etype, map, deg, elist, cnt);
    k_acc<<<512, 256, 0, stream>>>(srcp, dstp, etype, map, deg, elist, cnt, x, comp, acc8);
    k_fused<<<NPOS, 256, 0, stream>>>(eids, map, x, bases, root, bias,
                                      w1, b1, w2, b2, wp, bp, acc8, ent);
    k_gather<<<NPOS, HID, 0, stream>>>(eids, map, ent, out);
}

// Round 2
// 265.746 us; speedup vs baseline: 1.1420x; 1.1420x over previous
//
#include <hip/hip_runtime.h>

#define N_ENTITY 100000
#define D 128
#define HID 256
#define N_REL 48
#define N_BASES 8
#define N_EDGES 1000000
#define NPOS 1024   // 32*32 output positions
#define SLOTS 4     // slots per k_fused block

// ws layout in 4-byte elements
#define OFF_MAP   0                          // int[N_ENTITY] (padded)
#define OFF_DEG   100032                     // int[NPOS*N_REL]
#define OFF_ACC   149184                     // float[NPOS*N_BASES*D] = 1M
#define OFF_ENT   1197760                    // float[NPOS*HID]
// total = 1459904 elems ~ 5.84 MB

__global__ void k_register(const int* __restrict__ eids, int* __restrict__ map) {
    int pos = threadIdx.x;            // blockDim = 1024
    atomicMin(&map[eids[pos]], pos);  // owner slot = min position
}

// pass 1: per-(owner,relation) in-degree. No compaction, no hot counter.
__global__ void k_deg(const int* __restrict__ dst, const int* __restrict__ etype,
                      const int* __restrict__ map, int* __restrict__ deg) {
    int e = blockIdx.x * blockDim.x + threadIdx.x;
    if (e >= N_EDGES) return;
    int u = map[dst[e]];
    if (u < NPOS) atomicAdd(&deg[u * N_REL + etype[e]], 1);
}

// pass 2: accumulate normalized basis-weighted source rows into acc8[u][k][d].
__global__ __launch_bounds__(256) void k_acc2(
        const int* __restrict__ src, const int* __restrict__ dst,
        const int* __restrict__ etype, const int* __restrict__ map,
        const int* __restrict__ deg, const float* __restrict__ x,
        const float* __restrict__ comp, float* __restrict__ acc8) {
    __shared__ int msrc[256], mu[256], mt[256];
    __shared__ int nm;
    int tid = threadIdx.x;
    if (tid == 0) nm = 0;
    __syncthreads();
    int e = blockIdx.x * 256 + tid;
    bool match = false;
    int u = 0, t = 0, sv = 0;
    if (e < N_EDGES) {
        u = map[dst[e]];
        if (u < NPOS) { match = true; t = etype[e]; sv = src[e]; }
    }
    if (match) {
        int idx = atomicAdd(&nm, 1);
        msrc[idx] = sv; mu[idx] = u; mt[idx] = t;
    }
    __syncthreads();
    int n = nm;
    int d = tid & 127;
    for (int q = tid >> 7; q < n; q += 2) {          // 2 matches in flight
        int uu = mu[q], tt = mt[q];
        float xv = x[(size_t)msrc[q] * D + d];       // coalesced 512B row
        float nrm = 1.0f / fmaxf((float)deg[uu * N_REL + tt], 1.0f);
        float* ap = acc8 + (size_t)uu * (N_BASES * D) + d;
        #pragma unroll
        for (int k = 0; k < N_BASES; k++)
            atomicAdd(&ap[k * D], comp[tt * N_BASES + k] * nrm * xv);
    }
}

// fused RGCN-tail + MLP + projection for SLOTS slots per block.
__global__ __launch_bounds__(256) void k_fused(
        const int* __restrict__ eids, const float* __restrict__ x,
        const float* __restrict__ bases, const float* __restrict__ root,
        const float* __restrict__ bias, const float* __restrict__ w1,
        const float* __restrict__ b1, const float* __restrict__ w2,
        const float* __restrict__ b2, const float* __restrict__ wp,
        const float* __restrict__ bp, const float* __restrict__ acc8,
        float* __restrict__ ent) {
    int u0 = blockIdx.x * SLOTS;                      // 256 blocks
    __shared__ float xs[SLOTS][D];
    __shared__ float accs[SLOTS][N_BASES * D];
    __shared__ float hs[SLOTS][D];
    __shared__ float t1s[SLOTS][D / 2];
    __shared__ float h2s[SLOTS][D];
    __shared__ int enames[SLOTS];
    int tid = threadIdx.x;
    if (tid < SLOTS) enames[tid] = eids[u0 + tid];
    __syncthreads();
    for (int i = tid; i < SLOTS * D; i += 256) {
        int su = i >> 7, dd = i & 127;
        xs[su][dd] = x[(size_t)enames[su] * D + dd];
    }
    for (int i = tid; i < SLOTS * N_BASES * D; i += 256)
        ((float*)accs)[i] = acc8[(size_t)u0 * (N_BASES * D) + i];  // contiguous
    __syncthreads();

    // RGCN: hs = x@root + bias + sum_k acc_k@B_k + x. Two slots per thread.
    {
        int j = tid & 127, half = tid >> 7;
        int sa = half, sb = half + 2;
        float vA = bias[j], vB = vA;
        #pragma unroll 4
        for (int i = 0; i < D; i++) {
            float r = root[i * D + j];
            vA += xs[sa][i] * r;
            vB += xs[sb][i] * r;
        }
        #pragma unroll 4
        for (int idx = 0; idx < N_BASES * D; idx++) {
            float b = bases[(size_t)idx * D + j];     // bases[k][i][j] flat
            vA += accs[sa][idx] * b;
            vB += accs[sb][idx] * b;
        }
        hs[sa][j] = vA + xs[sa][j];
        hs[sb][j] = vB + xs[sb][j];
    }
    __syncthreads();
    // t1 = relu(h @ w1 + b1): SLOTS*64 = 256 outputs, one per thread
    {
        int su = tid >> 6, o = tid & 63;
        float s = b1[o];
        #pragma unroll 4
        for (int i = 0; i < D; i++) s += hs[su][i] * w1[i * (D / 2) + o];
        t1s[su][o] = fmaxf(s, 0.0f);
    }
    __syncthreads();
    // h2 = t1 @ w2 + b2 + h: SLOTS*128 = 512 outputs, two per thread
    {
        int j = tid & 127, half = tid >> 7;
        int sa = half, sb = half + 2;
        float vA = b2[j] + hs[sa][j], vB = b2[j] + hs[sb][j];
        #pragma unroll 4
        for (int i = 0; i < D / 2; i++) {
            float w = w2[i * D + j];
            vA += t1s[sa][i] * w;
            vB += t1s[sb][i] * w;
        }
        h2s[sa][j] = vA;
        h2s[sb][j] = vB;
    }
    __syncthreads();
    // ent = h2 @ wp + bp: SLOTS*256 = 1024 outputs, four per thread
    {
        int o = tid;
        float a0 = bp[o], a1 = a0, a2 = a0, a3 = a0;
        #pragma unroll 4
        for (int i = 0; i < D; i++) {
            float w = wp[i * HID + o];
            a0 += h2s[0][i] * w;
            a1 += h2s[1][i] * w;
            a2 += h2s[2][i] * w;
            a3 += h2s[3][i] * w;
        }
        ent[(size_t)(u0 + 0) * HID + o] = a0;
        ent[(size_t)(u0 + 1) * HID + o] = a1;
        ent[(size_t)(u0 + 2) * HID + o] = a2;
        ent[(size_t)(u0 + 3) * HID + o] = a3;
    }
}

__global__ void k_gather(const int* __restrict__ eids, const int* __restrict__ map,
                         const float* __restrict__ ent, float* __restrict__ out) {
    int pos = blockIdx.x;             // 1024 blocks of HID threads
    int u = map[eids[pos]];
    out[(size_t)pos * HID + threadIdx.x] = ent[(size_t)u * HID + threadIdx.x];
}

extern "C" void kernel_launch(void* const* d_in, const int* in_sizes, int n_in,
                              void* d_out, int out_size, void* d_ws, size_t ws_size,
                              hipStream_t stream) {
    const float* x     = (const float*)d_in[0];
    const float* bases = (const float*)d_in[1];
    const float* comp  = (const float*)d_in[2];
    const float* root  = (const float*)d_in[3];
    const float* bias  = (const float*)d_in[4];
    const float* w1    = (const float*)d_in[5];
    const float* b1    = (const float*)d_in[6];
    const float* w2    = (const float*)d_in[7];
    const float* b2    = (const float*)d_in[8];
    const float* wp    = (const float*)d_in[9];
    const float* bp    = (const float*)d_in[10];
    const int* eidx    = (const int*)d_in[11];
    const int* srcp    = eidx;
    const int* dstp    = eidx + N_EDGES;
    const int* etype   = (const int*)d_in[12];
    const int* eids    = (const int*)d_in[13];
    float* out = (float*)d_out;

    int*   ws    = (int*)d_ws;
    int*   map   = ws + OFF_MAP;
    int*   deg   = ws + OFF_DEG;
    float* acc8  = (float*)(ws + OFF_ACC);
    float* ent   = (float*)(ws + OFF_ENT);

    hipMemsetAsync(map, 0x7F, (size_t)N_ENTITY * sizeof(int), stream);
    hipMemsetAsync(deg, 0, (size_t)(NPOS * N_REL) * sizeof(int), stream);
    hipMemsetAsync(acc8, 0, (size_t)(NPOS * N_BASES * D) * sizeof(float), stream);

    k_register<<<1, NPOS, 0, stream>>>(eids, map);
    k_deg<<<(N_EDGES + 255) / 256, 256, 0, stream>>>(dstp, etype, map, deg);
    k_acc2<<<(N_EDGES + 255) / 256, 256, 0, stream>>>(srcp, dstp, etype, map, deg,
                                                      x, comp, acc8);
    k_fused<<<NPOS / SLOTS, 256, 0, stream>>>(eids, x, bases, root, bias,
                                              w1, b1, w2, b2, wp, bp, acc8, ent);
    k_gather<<<NPOS, HID, 0, stream>>>(eids, map, ent, out);
}

// Round 3
// 196.166 us; speedup vs baseline: 1.5470x; 1.3547x over previous
//
#include <hip/hip_runtime.h>

#define N_ENTITY 100000
#define D 128
#define HID 256
#define N_REL 48
#define N_BASES 8
#define N_EDGES 1000000
#define NPOS 1024
#define ECAP 96          // max staged edges per slot (Poisson(10); P(>96) ~ 0)
#define RECCAP 131072

// ws layout in 4-byte elements
#define OFF_MAP    0        // int[100032]  memset 0x7F
#define OFF_BITMAP 100032   // int[3200]    memset 0  (12.5 KB bitmap)
#define OFF_UCNT   103232   // int[1024]    memset 0
#define OFF_UCUR   104256   // int[1024]    memset 0
#define OFF_HDR    105280   // int[16]      memset 0
#define OFF_UOFF   105296   // int[1024]
#define OFF_RSRC   106320   // int[RECCAP]
#define OFF_RUT    237392   // int[RECCAP]
#define OFF_BSRC   368464   // int[RECCAP]
#define OFF_BT     499536   // int[RECCAP]
#define OFF_ENT    630608   // float[NPOS*HID]
// end = 892752 ints ~ 3.57 MB

__global__ void k_register(const int* __restrict__ eids, int* __restrict__ map,
                           unsigned int* __restrict__ bitmap) {
    int pos = threadIdx.x;                 // blockDim = 1024
    int e = eids[pos];
    atomicMin(&map[e], pos);
    atomicOr(&bitmap[e >> 5], 1u << (e & 31));
}

// scan 1M edges: bitmap filter (L1), compact matches per block, count per slot
__global__ __launch_bounds__(256) void k_count(
        const int* __restrict__ src, const int* __restrict__ dst,
        const int* __restrict__ etype, const int* __restrict__ map,
        const unsigned int* __restrict__ bitmap, int* __restrict__ ucnt,
        int* __restrict__ rsrc, int* __restrict__ rut, int* __restrict__ hdr) {
    __shared__ int lsrc[256], lut[256];
    __shared__ int cnt, base;
    int tid = threadIdx.x;
    if (tid == 0) cnt = 0;
    __syncthreads();
    int e = blockIdx.x * 256 + tid;
    if (e < N_EDGES) {
        int d = dst[e];
        if ((bitmap[d >> 5] >> (d & 31)) & 1u) {
            int u = map[d];                 // true match (bit set only for targets)
            int t = etype[e];
            int s = src[e];
            int idx = atomicAdd(&cnt, 1);
            lsrc[idx] = s;
            lut[idx] = (u << 6) | t;
            atomicAdd(&ucnt[u], 1);
        }
    }
    __syncthreads();
    if (tid == 0) base = atomicAdd(&hdr[0], cnt);
    __syncthreads();
    for (int i = tid; i < cnt; i += 256) {
        int p = base + i;
        if (p < RECCAP) { rsrc[p] = lsrc[i]; rut[p] = lut[i]; }
    }
}

__global__ void k_prefix(const int* __restrict__ ucnt, int* __restrict__ uoff) {
    __shared__ int buf[NPOS];
    int tid = threadIdx.x;                 // blockDim = 1024
    int v = ucnt[tid];
    buf[tid] = v;
    __syncthreads();
    for (int off = 1; off < NPOS; off <<= 1) {
        int t = (tid >= off) ? buf[tid - off] : 0;
        __syncthreads();
        buf[tid] += t;
        __syncthreads();
    }
    uoff[tid] = buf[tid] - v;
}

__global__ void k_bucket(const int* __restrict__ rsrc, const int* __restrict__ rut,
                         const int* __restrict__ hdr, const int* __restrict__ uoff,
                         int* __restrict__ ucur, int* __restrict__ bsrc,
                         int* __restrict__ bt) {
    int n = hdr[0];
    if (n > RECCAP) n = RECCAP;
    int stride = gridDim.x * blockDim.x;
    for (int i = blockIdx.x * blockDim.x + threadIdx.x; i < n; i += stride) {
        int ut = rut[i];
        int u = ut >> 6;
        int pos = uoff[u] + atomicAdd(&ucur[u], 1);
        if (pos < RECCAP) { bsrc[pos] = rsrc[i]; bt[pos] = ut & 63; }
    }
}

// fully fused: per-slot edge accumulation (registers) + RGCN + MLP + projection.
// 512 threads, 2 slots per block, 512 blocks.
__global__ __launch_bounds__(512) void k_fused2(
        const int* __restrict__ eids, const int* __restrict__ ucnt,
        const int* __restrict__ uoff, const int* __restrict__ bsrc,
        const int* __restrict__ bt, const float* __restrict__ x,
        const float* __restrict__ comp, const float* __restrict__ bases,
        const float* __restrict__ root, const float* __restrict__ bias,
        const float* __restrict__ w1, const float* __restrict__ b1,
        const float* __restrict__ w2, const float* __restrict__ b2,
        const float* __restrict__ wp, const float* __restrict__ bp,
        float* __restrict__ ent) {
    __shared__ float xs[2][D];
    __shared__ float accs[2][N_BASES * D];   // 8 KB
    __shared__ float hs[2][D];
    __shared__ float t1s[2][D / 2];
    __shared__ float h2s[2][D];
    __shared__ float part[1024];             // reused combine buffer, 4 KB
    __shared__ float ctab[ECAP][N_BASES];    // 3 KB
    __shared__ int esrc[ECAP], eti[ECAP];
    __shared__ int deg48[N_REL];
    __shared__ int enames[2];

    int tid = threadIdx.x;
    int u0 = blockIdx.x * 2;
    if (tid < 2) enames[tid] = eids[u0 + tid];
    __syncthreads();
    if (tid < 256) {
        int s = tid >> 7, dd = tid & 127;
        xs[s][dd] = x[(size_t)enames[s] * D + dd];
    }

    // ---- Phase A: per-slot edge accumulation into accs (no atomics) ----
    {
        int d = tid & 127;
        int kg = tid >> 7;                   // 0..3 -> k pair {2kg, 2kg+1}
        for (int s = 0; s < 2; ++s) {
            int u = u0 + s;
            int n = ucnt[u]; if (n > ECAP) n = ECAP;
            int start = uoff[u];
            if (tid < N_REL) deg48[tid] = 0;
            if (tid < n) { esrc[tid] = bsrc[start + tid]; eti[tid] = bt[start + tid]; }
            __syncthreads();
            if (tid < n) atomicAdd(&deg48[eti[tid]], 1);
            __syncthreads();
            for (int ii = tid; ii < n * N_BASES; ii += 512) {
                int i = ii >> 3, k = ii & 7;
                int t = eti[i];
                ctab[i][k] = comp[t * N_BASES + k] / (float)max(deg48[t], 1);
            }
            __syncthreads();
            float a0 = 0.0f, a1 = 0.0f;
            #pragma unroll 4
            for (int i = 0; i < n; ++i) {
                float xv = x[(size_t)esrc[i] * D + d];
                a0 += ctab[i][2 * kg] * xv;
                a1 += ctab[i][2 * kg + 1] * xv;
            }
            accs[s][(2 * kg) * D + d] = a0;
            accs[s][(2 * kg + 1) * D + d] = a1;
            __syncthreads();
        }
    }

    // ---- Phase B: h = x@root + sum_k acc_k@B_k + bias + x ----
    {
        int j = tid & 127;
        int kq = tid >> 7;                   // K quarter 0..3
        float pA = 0.0f, pB = 0.0f;
        int i0 = 32 * kq;
        #pragma unroll 8
        for (int ii = 0; ii < 32; ++ii) {
            float r = root[(i0 + ii) * D + j];
            pA += xs[0][i0 + ii] * r;
            pB += xs[1][i0 + ii] * r;
        }
        int x0 = 256 * kq;
        #pragma unroll 8
        for (int ii = 0; ii < 256; ++ii) {
            int idx = x0 + ii;
            float w = bases[(size_t)idx * D + j];
            pA += accs[0][idx] * w;
            pB += accs[1][idx] * w;
        }
        part[kq * 256 + j] = pA;             // [kq][s=0][j]
        part[kq * 256 + 128 + j] = pB;       // [kq][s=1][j]
    }
    __syncthreads();
    if (tid < 256) {
        int s = tid >> 7, j = tid & 127;
        float v = bias[j] + xs[s][j];
        #pragma unroll
        for (int q = 0; q < 4; ++q) v += part[q * 256 + s * 128 + j];
        hs[s][j] = v;
    }
    __syncthreads();

    // ---- Phase C1: t1 = relu(h @ w1 + b1)  (64 outputs/slot) ----
    {
        int o = tid & 63;
        int q = tid >> 6;                    // 0..7, K chunk of 16
        float p0 = 0.0f, p1 = 0.0f;
        int i0 = 16 * q;
        #pragma unroll
        for (int ii = 0; ii < 16; ++ii) {
            float w = w1[(i0 + ii) * (D / 2) + o];
            p0 += hs[0][i0 + ii] * w;
            p1 += hs[1][i0 + ii] * w;
        }
        part[q * 128 + o] = p0;
        part[q * 128 + 64 + o] = p1;
    }
    __syncthreads();
    if (tid < 128) {
        int s = tid >> 6, o = tid & 63;
        float v = b1[o];
        #pragma unroll
        for (int q = 0; q < 8; ++q) v += part[q * 128 + s * 64 + o];
        t1s[s][o] = fmaxf(v, 0.0f);
    }
    __syncthreads();

    // ---- Phase C2: h2 = t1 @ w2 + b2 + h ----
    {
        int j = tid & 127;
        int q = tid >> 7;                    // 0..3, K chunk of 16 (K=64)
        float p0 = 0.0f, p1 = 0.0f;
        int i0 = 16 * q;
        #pragma unroll
        for (int ii = 0; ii < 16; ++ii) {
            float w = w2[(i0 + ii) * D + j];
            p0 += t1s[0][i0 + ii] * w;
            p1 += t1s[1][i0 + ii] * w;
        }
        part[q * 256 + j] = p0;
        part[q * 256 + 128 + j] = p1;
    }
    __syncthreads();
    if (tid < 256) {
        int s = tid >> 7, j = tid & 127;
        float v = b2[j] + hs[s][j];
        #pragma unroll
        for (int q = 0; q < 4; ++q) v += part[q * 256 + s * 128 + j];
        h2s[s][j] = v;
    }
    __syncthreads();

    // ---- Phase C3: ent = h2 @ wp + bp  (256 outputs/slot) ----
    {
        int o = tid & 255;
        int h = tid >> 8;                    // K half 0..1 (K=128)
        float p0 = 0.0f, p1 = 0.0f;
        int i0 = 64 * h;
        #pragma unroll 8
        for (int ii = 0; ii < 64; ++ii) {
            float w = wp[(i0 + ii) * HID + o];
            p0 += h2s[0][i0 + ii] * w;
            p1 += h2s[1][i0 + ii] * w;
        }
        part[h * 512 + o] = p0;              // [h][s=0][o]
        part[h * 512 + 256 + o] = p1;        // [h][s=1][o]
    }
    __syncthreads();
    {
        int s = tid >> 8, o = tid & 255;
        float v = bp[o] + part[s * 256 + o] + part[512 + s * 256 + o];
        ent[(size_t)(u0 + s) * HID + o] = v;
    }
}

__global__ void k_gather(const int* __restrict__ eids, const int* __restrict__ map,
                         const float* __restrict__ ent, float* __restrict__ out) {
    int pos = blockIdx.x;                  // 1024 blocks of HID threads
    int u = map[eids[pos]];
    out[(size_t)pos * HID + threadIdx.x] = ent[(size_t)u * HID + threadIdx.x];
}

extern "C" void kernel_launch(void* const* d_in, const int* in_sizes, int n_in,
                              void* d_out, int out_size, void* d_ws, size_t ws_size,
                              hipStream_t stream) {
    const float* x     = (const float*)d_in[0];
    const float* bases = (const float*)d_in[1];
    const float* comp  = (const float*)d_in[2];
    const float* root  = (const float*)d_in[3];
    const float* bias  = (const float*)d_in[4];
    const float* w1    = (const float*)d_in[5];
    const float* b1    = (const float*)d_in[6];
    const float* w2    = (const float*)d_in[7];
    const float* b2    = (const float*)d_in[8];
    const float* wp    = (const float*)d_in[9];
    const float* bp    = (const float*)d_in[10];
    const int* eidx    = (const int*)d_in[11];
    const int* srcp    = eidx;
    const int* dstp    = eidx + N_EDGES;
    const int* etype   = (const int*)d_in[12];
    const int* eids    = (const int*)d_in[13];
    float* out = (float*)d_out;

    int* ws = (int*)d_ws;
    int* map            = ws + OFF_MAP;
    unsigned int* bmap  = (unsigned int*)(ws + OFF_BITMAP);
    int* ucnt           = ws + OFF_UCNT;
    int* ucur           = ws + OFF_UCUR;
    int* hdr            = ws + OFF_HDR;
    int* uoff           = ws + OFF_UOFF;
    int* rsrc           = ws + OFF_RSRC;
    int* rut            = ws + OFF_RUT;
    int* bsrc           = ws + OFF_BSRC;
    int* bt             = ws + OFF_BT;
    float* ent          = (float*)(ws + OFF_ENT);

    hipMemsetAsync(map, 0x7F, (size_t)100032 * sizeof(int), stream);
    // bitmap + ucnt + ucur + hdr are contiguous: one memset
    hipMemsetAsync(ws + OFF_BITMAP, 0, (size_t)(3200 + 1024 + 1024 + 16) * sizeof(int), stream);

    k_register<<<1, NPOS, 0, stream>>>(eids, map, bmap);
    k_count<<<(N_EDGES + 255) / 256, 256, 0, stream>>>(srcp, dstp, etype, map, bmap,
                                                       ucnt, rsrc, rut, hdr);
    k_prefix<<<1, NPOS, 0, stream>>>(ucnt, uoff);
    k_bucket<<<64, 256, 0, stream>>>(rsrc, rut, hdr, uoff, ucur, bsrc, bt);
    k_fused2<<<NPOS / 2, 512, 0, stream>>>(eids, ucnt, uoff, bsrc, bt, x, comp,
                                           bases, root, bias, w1, b1, w2, b2,
                                           wp, bp, ent);
    k_gather<<<NPOS, HID, 0, stream>>>(eids, map, ent, out);
}

// Round 4
// 151.676 us; speedup vs baseline: 2.0008x; 1.2933x over previous
//
#include <hip/hip_runtime.h>

#define N_ENTITY 100000
#define D 128
#define HID 256
#define N_REL 48
#define N_BASES 8
#define N_EDGES 1000000
#define NPOS 1024
#define ECAP 96          // bucket capacity per slot (max in-deg of 1019 targets ~30)

// ws layout in 4-byte elements
#define OFF_MAP    0        // int[100032]  memset 0x7F
#define OFF_BITMAP 100032   // int[3200]    memset 0  (12.5 KB bitmap)
#define OFF_UCNT   103232   // int[1024]    memset 0
#define OFF_BKT    104256   // int[NPOS*ECAP] packed (src | type<<17)
#define OFF_ENT    202560   // float[NPOS*HID]
// end = 464704 ints ~ 1.86 MB

__global__ void k_register(const int* __restrict__ eids, int* __restrict__ map,
                           unsigned int* __restrict__ bitmap) {
    int pos = threadIdx.x;                 // blockDim = 1024
    int e = eids[pos];
    atomicMin(&map[e], pos);
    atomicOr(&bitmap[e >> 5], 1u << (e & 31));
}

// scan 1M edges (4 per thread): bitmap filter (L1-resident), matches go
// straight into fixed-capacity per-slot buckets. No hot counter anywhere.
__global__ __launch_bounds__(256) void k_count(
        const int* __restrict__ src, const int* __restrict__ dst,
        const int* __restrict__ etype, const int* __restrict__ map,
        const unsigned int* __restrict__ bitmap, int* __restrict__ ucnt,
        int* __restrict__ bkt) {
    int base = (blockIdx.x * 256 + threadIdx.x) * 4;
    if (base >= N_EDGES) return;
    const int4 d4 = *reinterpret_cast<const int4*>(dst + base);
    #pragma unroll
    for (int q = 0; q < 4; ++q) {
        int d = (&d4.x)[q];
        if ((bitmap[d >> 5] >> (d & 31)) & 1u) {
            int e = base + q;
            int u = map[d];                 // owner slot (bitmap hit => valid)
            int pos = atomicAdd(&ucnt[u], 1);
            if (pos < ECAP)
                bkt[u * ECAP + pos] = src[e] | (etype[e] << 17);
        }
    }
}

// fully fused: per-slot edge accumulation (LDS/regs) + RGCN + MLP + projection.
// 512 threads, 2 slots per block, 512 blocks.
__global__ __launch_bounds__(512) void k_fused2(
        const int* __restrict__ eids, const int* __restrict__ ucnt,
        const int* __restrict__ bkt, const float* __restrict__ x,
        const float* __restrict__ comp, const float* __restrict__ bases,
        const float* __restrict__ root, const float* __restrict__ bias,
        const float* __restrict__ w1, const float* __restrict__ b1,
        const float* __restrict__ w2, const float* __restrict__ b2,
        const float* __restrict__ wp, const float* __restrict__ bp,
        float* __restrict__ ent) {
    __shared__ float xs[2][D];
    __shared__ float accs[2][N_BASES * D];   // 8 KB
    __shared__ float hs[2][D];
    __shared__ float t1s[2][D / 2];
    __shared__ float h2s[2][D];
    __shared__ float part[1024];             // reused combine buffer, 4 KB
    __shared__ float ctab[ECAP][N_BASES];    // 3 KB
    __shared__ int esrc[ECAP], eti[ECAP];
    __shared__ int deg48[N_REL];
    __shared__ int enames[2];

    int tid = threadIdx.x;
    int u0 = blockIdx.x * 2;
    if (tid < 2) enames[tid] = eids[u0 + tid];
    __syncthreads();
    if (tid < 256) {
        int s = tid >> 7, dd = tid & 127;
        xs[s][dd] = x[(size_t)enames[s] * D + dd];
    }

    // ---- Phase A: per-slot edge accumulation into accs (no atomics) ----
    {
        int d = tid & 127;
        int kg = tid >> 7;                   // 0..3 -> k pair {2kg, 2kg+1}
        for (int s = 0; s < 2; ++s) {
            int u = u0 + s;
            int n = ucnt[u]; if (n > ECAP) n = ECAP;
            if (tid < N_REL) deg48[tid] = 0;
            if (tid < n) {
                int w = bkt[u * ECAP + tid];
                esrc[tid] = w & 0x1FFFF;
                eti[tid] = w >> 17;
            }
            __syncthreads();
            if (tid < n) atomicAdd(&deg48[eti[tid]], 1);
            __syncthreads();
            for (int ii = tid; ii < n * N_BASES; ii += 512) {
                int i = ii >> 3, k = ii & 7;
                int t = eti[i];
                ctab[i][k] = comp[t * N_BASES + k] / (float)max(deg48[t], 1);
            }
            __syncthreads();
            float a0 = 0.0f, a1 = 0.0f;
            #pragma unroll 4
            for (int i = 0; i < n; ++i) {
                float xv = x[(size_t)esrc[i] * D + d];
                a0 += ctab[i][2 * kg] * xv;
                a1 += ctab[i][2 * kg + 1] * xv;
            }
            accs[s][(2 * kg) * D + d] = a0;
            accs[s][(2 * kg + 1) * D + d] = a1;
            __syncthreads();
        }
    }

    // ---- Phase B: h = x@root + sum_k acc_k@B_k + bias + x ----
    {
        int j = tid & 127;
        int kq = tid >> 7;                   // K quarter 0..3
        float pA = 0.0f, pB = 0.0f;
        int i0 = 32 * kq;
        #pragma unroll 8
        for (int ii = 0; ii < 32; ++ii) {
            float r = root[(i0 + ii) * D + j];
            pA += xs[0][i0 + ii] * r;
            pB += xs[1][i0 + ii] * r;
        }
        int x0 = 256 * kq;
        #pragma unroll 8
        for (int ii = 0; ii < 256; ++ii) {
            int idx = x0 + ii;
            float w = bases[(size_t)idx * D + j];
            pA += accs[0][idx] * w;
            pB += accs[1][idx] * w;
        }
        part[kq * 256 + j] = pA;             // [kq][s=0][j]
        part[kq * 256 + 128 + j] = pB;       // [kq][s=1][j]
    }
    __syncthreads();
    if (tid < 256) {
        int s = tid >> 7, j = tid & 127;
        float v = bias[j] + xs[s][j];
        #pragma unroll
        for (int q = 0; q < 4; ++q) v += part[q * 256 + s * 128 + j];
        hs[s][j] = v;
    }
    __syncthreads();

    // ---- Phase C1: t1 = relu(h @ w1 + b1)  (64 outputs/slot) ----
    {
        int o = tid & 63;
        int q = tid >> 6;                    // 0..7, K chunk of 16
        float p0 = 0.0f, p1 = 0.0f;
        int i0 = 16 * q;
        #pragma unroll
        for (int ii = 0; ii < 16; ++ii) {
            float w = w1[(i0 + ii) * (D / 2) + o];
            p0 += hs[0][i0 + ii] * w;
            p1 += hs[1][i0 + ii] * w;
        }
        part[q * 128 + o] = p0;
        part[q * 128 + 64 + o] = p1;
    }
    __syncthreads();
    if (tid < 128) {
        int s = tid >> 6, o = tid & 63;
        float v = b1[o];
        #pragma unroll
        for (int q = 0; q < 8; ++q) v += part[q * 128 + s * 64 + o];
        t1s[s][o] = fmaxf(v, 0.0f);
    }
    __syncthreads();

    // ---- Phase C2: h2 = t1 @ w2 + b2 + h ----
    {
        int j = tid & 127;
        int q = tid >> 7;                    // 0..3, K chunk of 16 (K=64)
        float p0 = 0.0f, p1 = 0.0f;
        int i0 = 16 * q;
        #pragma unroll
        for (int ii = 0; ii < 16; ++ii) {
            float w = w2[(i0 + ii) * D + j];
            p0 += t1s[0][i0 + ii] * w;
            p1 += t1s[1][i0 + ii] * w;
        }
        part[q * 256 + j] = p0;
        part[q * 256 + 128 + j] = p1;
    }
    __syncthreads();
    if (tid < 256) {
        int s = tid >> 7, j = tid & 127;
        float v = b2[j] + hs[s][j];
        #pragma unroll
        for (int q = 0; q < 4; ++q) v += part[q * 256 + s * 128 + j];
        h2s[s][j] = v;
    }
    __syncthreads();

    // ---- Phase C3: ent = h2 @ wp + bp  (256 outputs/slot) ----
    {
        int o = tid & 255;
        int h = tid >> 8;                    // K half 0..1 (K=128)
        float p0 = 0.0f, p1 = 0.0f;
        int i0 = 64 * h;
        #pragma unroll 8
        for (int ii = 0; ii < 64; ++ii) {
            float w = wp[(i0 + ii) * HID + o];
            p0 += h2s[0][i0 + ii] * w;
            p1 += h2s[1][i0 + ii] * w;
        }
        part[h * 512 + o] = p0;              // [h][s=0][o]
        part[h * 512 + 256 + o] = p1;        // [h][s=1][o]
    }
    __syncthreads();
    {
        int s = tid >> 8, o = tid & 255;
        float v = bp[o] + part[s * 256 + o] + part[512 + s * 256 + o];
        ent[(size_t)(u0 + s) * HID + o] = v;
    }
}

__global__ void k_gather(const int* __restrict__ eids, const int* __restrict__ map,
                         const float* __restrict__ ent, float* __restrict__ out) {
    int pos = blockIdx.x;                  // 1024 blocks of HID threads
    int u = map[eids[pos]];
    out[(size_t)pos * HID + threadIdx.x] = ent[(size_t)u * HID + threadIdx.x];
}

extern "C" void kernel_launch(void* const* d_in, const int* in_sizes, int n_in,
                              void* d_out, int out_size, void* d_ws, size_t ws_size,
                              hipStream_t stream) {
    const float* x     = (const float*)d_in[0];
    const float* bases = (const float*)d_in[1];
    const float* comp  = (const float*)d_in[2];
    const float* root  = (const float*)d_in[3];
    const float* bias  = (const float*)d_in[4];
    const float* w1    = (const float*)d_in[5];
    const float* b1    = (const float*)d_in[6];
    const float* w2    = (const float*)d_in[7];
    const float* b2    = (const float*)d_in[8];
    const float* wp    = (const float*)d_in[9];
    const float* bp    = (const float*)d_in[10];
    const int* eidx    = (const int*)d_in[11];
    const int* srcp    = eidx;
    const int* dstp    = eidx + N_EDGES;
    const int* etype   = (const int*)d_in[12];
    const int* eids    = (const int*)d_in[13];
    float* out = (float*)d_out;

    int* ws = (int*)d_ws;
    int* map            = ws + OFF_MAP;
    unsigned int* bmap  = (unsigned int*)(ws + OFF_BITMAP);
    int* ucnt           = ws + OFF_UCNT;
    int* bkt            = ws + OFF_BKT;
    float* ent          = (float*)(ws + OFF_ENT);

    hipMemsetAsync(map, 0x7F, (size_t)100032 * sizeof(int), stream);
    hipMemsetAsync(ws + OFF_BITMAP, 0, (size_t)(3200 + 1024) * sizeof(int), stream);

    k_register<<<1, NPOS, 0, stream>>>(eids, map, bmap);
    k_count<<<(N_EDGES / 4 + 255) / 256, 256, 0, stream>>>(srcp, dstp, etype, map,
                                                           bmap, ucnt, bkt);
    k_fused2<<<NPOS / 2, 512, 0, stream>>>(eids, ucnt, bkt, x, comp,
                                           bases, root, bias, w1, b1, w2, b2,
                                           wp, bp, ent);
    k_gather<<<NPOS, HID, 0, stream>>>(eids, map, ent, out);
}

// Round 6
// 146.500 us; speedup vs baseline: 2.0715x; 1.0353x over previous
//
#include <hip/hip_runtime.h>

#define N_ENTITY 100000
#define D 128
#define HID 256
#define N_REL 48
#define N_BASES 8
#define N_EDGES 1000000
#define NPOS 1024
#define ECAP 96          // bucket capacity per slot (max in-deg of ~1019 targets ~35)

// ws layout in 4-byte elements
#define OFF_MAP    0        // int[100032]  memset 0x7F
#define OFF_BITMAP 100032   // int[3200]    cleared in k_register
#define OFF_UCNT   103232   // int[1024]    cleared in k_register
#define OFF_BKT    104256   // int[NPOS*ECAP] packed (src | type<<17)
#define OFF_ENT    202560   // float[NPOS*HID]
// end = 464704 ints ~ 1.86 MB

__global__ void k_register(const int* __restrict__ eids, int* __restrict__ map,
                           unsigned int* __restrict__ bitmap, int* __restrict__ ucnt) {
    int tid = threadIdx.x;                 // blockDim = 1024, single block
    for (int i = tid; i < 3200; i += 1024) bitmap[i] = 0u;
    ucnt[tid] = 0;
    __syncthreads();
    int e = eids[tid];
    atomicMin(&map[e], tid);
    atomicOr(&bitmap[e >> 5], 1u << (e & 31));
}

// scan 1M edges (4 per thread): bitmap filter (L1-resident); matches go
// straight into fixed-capacity per-slot buckets. Atomics spread over 1024 addrs.
__global__ __launch_bounds__(256) void k_count(
        const int* __restrict__ src, const int* __restrict__ dst,
        const int* __restrict__ etype, const int* __restrict__ map,
        const unsigned int* __restrict__ bitmap, int* __restrict__ ucnt,
        int* __restrict__ bkt) {
    int base = (blockIdx.x * 256 + threadIdx.x) * 4;
    if (base >= N_EDGES) return;
    const int4 d4 = *reinterpret_cast<const int4*>(dst + base);
    #pragma unroll
    for (int q = 0; q < 4; ++q) {
        int d = (&d4.x)[q];
        if ((bitmap[d >> 5] >> (d & 31)) & 1u) {
            int e = base + q;
            int u = map[d];
            int pos = atomicAdd(&ucnt[u], 1);
            if (pos < ECAP)
                bkt[u * ECAP + pos] = src[e] | (etype[e] << 17);
        }
    }
}

// fully fused: edge accumulation + RGCN + MLP + projection. 512 threads,
// 2 slots/block, 512 blocks. All weight streams are float4-coalesced with
// K-split partials combined through LDS.
__global__ __launch_bounds__(512) void k_fused2(
        const int* __restrict__ eids, const int* __restrict__ ucnt,
        const int* __restrict__ bkt, const float* __restrict__ x,
        const float* __restrict__ comp, const float* __restrict__ bases,
        const float* __restrict__ root, const float* __restrict__ bias,
        const float* __restrict__ w1, const float* __restrict__ b1,
        const float* __restrict__ w2, const float* __restrict__ b2,
        const float* __restrict__ wp, const float* __restrict__ bp,
        float* __restrict__ ent) {
    __shared__ float xs[2][D];
    __shared__ float accs[2][N_BASES * D];   // 8 KB
    __shared__ float hs[2][D];
    __shared__ float t1s[2][D / 2];
    __shared__ float h2s[2][D];
    __shared__ float part[4096];             // 16 KB K-split combine buffer
    __shared__ float ctab[ECAP][N_BASES];    // 3 KB
    __shared__ int esrc[ECAP], eti[ECAP];
    __shared__ int deg48[N_REL];
    __shared__ int enames[2];

    int tid = threadIdx.x;
    int u0 = blockIdx.x * 2;
    if (tid < 2) enames[tid] = eids[u0 + tid];
    __syncthreads();
    if (tid < 256) {
        int s = tid >> 7, dd = tid & 127;
        xs[s][dd] = x[(size_t)enames[s] * D + dd];
    }

    // ---- Phase A: per-slot edge accumulation into accs (no global atomics) ----
    {
        int d = tid & 127;
        int kg = tid >> 7;                   // 0..3 -> basis pair {2kg, 2kg+1}
        for (int s = 0; s < 2; ++s) {
            int u = u0 + s;
            int n = ucnt[u]; if (n > ECAP) n = ECAP;
            if (tid < N_REL) deg48[tid] = 0;
            if (tid < n) {
                int w = bkt[u * ECAP + tid];
                esrc[tid] = w & 0x1FFFF;
                eti[tid] = w >> 17;
            }
            __syncthreads();
            if (tid < n) atomicAdd(&deg48[eti[tid]], 1);
            __syncthreads();
            for (int ii = tid; ii < n * N_BASES; ii += 512) {
                int i = ii >> 3, k = ii & 7;
                int t = eti[i];
                ctab[i][k] = comp[t * N_BASES + k] / (float)max(deg48[t], 1);
            }
            __syncthreads();
            float a0 = 0.0f, a1 = 0.0f;
            #pragma unroll 4
            for (int i = 0; i < n; ++i) {
                float xv = x[(size_t)esrc[i] * D + d];
                a0 += ctab[i][2 * kg] * xv;
                a1 += ctab[i][2 * kg + 1] * xv;
            }
            accs[s][(2 * kg) * D + d] = a0;
            accs[s][(2 * kg + 1) * D + d] = a1;
            __syncthreads();
        }
    }

    // ---- Phase B: h = x@root + sum_k acc_k@B_k + bias + x ----
    // thread = (jq 0..31, kc 0..15): 4 output cols, K-chunk. float4 weight rows.
    {
        int jq = tid & 31, kc = tid >> 5;
        int j0 = jq * 4;
        float4 pA = {0, 0, 0, 0}, pB = {0, 0, 0, 0};
        #pragma unroll 8
        for (int ii = 0; ii < 8; ++ii) {          // root rows kc*8..+7
            int r = kc * 8 + ii;
            float4 w = *reinterpret_cast<const float4*>(root + r * D + j0);
            float aA = xs[0][r], aB = xs[1][r];
            pA.x += aA * w.x; pA.y += aA * w.y; pA.z += aA * w.z; pA.w += aA * w.w;
            pB.x += aB * w.x; pB.y += aB * w.y; pB.z += aB * w.z; pB.w += aB * w.w;
        }
        #pragma unroll 8
        for (int ii = 0; ii < 64; ++ii) {         // bases rows kc*64..+63
            int r = kc * 64 + ii;
            float4 w = *reinterpret_cast<const float4*>(bases + (size_t)r * D + j0);
            float aA = accs[0][r], aB = accs[1][r];
            pA.x += aA * w.x; pA.y += aA * w.y; pA.z += aA * w.z; pA.w += aA * w.w;
            pB.x += aB * w.x; pB.y += aB * w.y; pB.z += aB * w.z; pB.w += aB * w.w;
        }
        float* p0 = part + kc * 256 + j0;         // [kc][s][128]
        p0[0] = pA.x; p0[1] = pA.y; p0[2] = pA.z; p0[3] = pA.w;
        float* p1 = p0 + 128;
        p1[0] = pB.x; p1[1] = pB.y; p1[2] = pB.z; p1[3] = pB.w;
    }
    __syncthreads();
    if (tid < 256) {
        int s = tid >> 7, j = tid & 127;
        float v = bias[j] + xs[s][j];
        #pragma unroll
        for (int q = 0; q < 16; ++q) v += part[q * 256 + s * 128 + j];
        hs[s][j] = v;
    }
    __syncthreads();

    // ---- Phase C1: t1 = relu(h @ w1 + b1)   w1:[128][64] ----
    // thread = (oq 0..15, kc 0..31): 4 cols, 4 K-rows each.
    {
        int oq = tid & 15, kc = tid >> 4;
        int o0 = oq * 4;
        float4 pA = {0, 0, 0, 0}, pB = {0, 0, 0, 0};
        #pragma unroll
        for (int ii = 0; ii < 4; ++ii) {
            int r = kc * 4 + ii;
            float4 w = *reinterpret_cast<const float4*>(w1 + r * (D / 2) + o0);
            float aA = hs[0][r], aB = hs[1][r];
            pA.x += aA * w.x; pA.y += aA * w.y; pA.z += aA * w.z; pA.w += aA * w.w;
            pB.x += aB * w.x; pB.y += aB * w.y; pB.z += aB * w.z; pB.w += aB * w.w;
        }
        float* p0 = part + kc * 128 + o0;         // [kc][s][64]
        p0[0] = pA.x; p0[1] = pA.y; p0[2] = pA.z; p0[3] = pA.w;
        float* p1 = p0 + 64;
        p1[0] = pB.x; p1[1] = pB.y; p1[2] = pB.z; p1[3] = pB.w;
    }
    __syncthreads();
    if (tid < 128) {
        int s = tid >> 6, o = tid & 63;
        float v = b1[o];
        #pragma unroll
        for (int q = 0; q < 32; ++q) v += part[q * 128 + s * 64 + o];
        t1s[s][o] = fmaxf(v, 0.0f);
    }
    __syncthreads();

    // ---- Phase C2: h2 = t1 @ w2 + b2 + h   w2:[64][128] ----
    // thread = (jq 0..31, kc 0..15): 4 cols, 4 K-rows each.
    {
        int jq = tid & 31, kc = tid >> 5;
        int j0 = jq * 4;
        float4 pA = {0, 0, 0, 0}, pB = {0, 0, 0, 0};
        #pragma unroll
        for (int ii = 0; ii < 4; ++ii) {
            int r = kc * 4 + ii;
            float4 w = *reinterpret_cast<const float4*>(w2 + r * D + j0);
            float aA = t1s[0][r], aB = t1s[1][r];
            pA.x += aA * w.x; pA.y += aA * w.y; pA.z += aA * w.z; pA.w += aA * w.w;
            pB.x += aB * w.x; pB.y += aB * w.y; pB.z += aB * w.z; pB.w += aB * w.w;
        }
        float* p0 = part + kc * 256 + j0;         // [kc][s][128]
        p0[0] = pA.x; p0[1] = pA.y; p0[2] = pA.z; p0[3] = pA.w;
        float* p1 = p0 + 128;
        p1[0] = pB.x; p1[1] = pB.y; p1[2] = pB.z; p1[3] = pB.w;
    }
    __syncthreads();
    if (tid < 256) {
        int s = tid >> 7, j = tid & 127;
        float v = b2[j] + hs[s][j];
        #pragma unroll
        for (int q = 0; q < 16; ++q) v += part[q * 256 + s * 128 + j];
        h2s[s][j] = v;
    }
    __syncthreads();

    // ---- Phase C3: ent = h2 @ wp + bp   wp:[128][256] ----
    // thread = (oq 0..63, kc 0..7): 4 cols, 16 K-rows each.
    {
        int oq = tid & 63, kc = tid >> 6;
        int o0 = oq * 4;
        float4 pA = {0, 0, 0, 0}, pB = {0, 0, 0, 0};
        #pragma unroll 8
        for (int ii = 0; ii < 16; ++ii) {
            int r = kc * 16 + ii;
            float4 w = *reinterpret_cast<const float4*>(wp + r * HID + o0);
            float aA = h2s[0][r], aB = h2s[1][r];
            pA.x += aA * w.x; pA.y += aA * w.y; pA.z += aA * w.z; pA.w += aA * w.w;
            pB.x += aB * w.x; pB.y += aB * w.y; pB.z += aB * w.z; pB.w += aB * w.w;
        }
        float* p0 = part + kc * 512 + o0;         // [kc][s][256]
        p0[0] = pA.x; p0[1] = pA.y; p0[2] = pA.z; p0[3] = pA.w;
        float* p1 = p0 + 256;
        p1[0] = pB.x; p1[1] = pB.y; p1[2] = pB.z; p1[3] = pB.w;
    }
    __syncthreads();
    {
        int s = tid >> 8, o = tid & 255;
        float v = bp[o];
        #pragma unroll
        for (int q = 0; q < 8; ++q) v += part[q * 512 + s * 256 + o];
        ent[(size_t)(u0 + s) * HID + o] = v;
    }
}

__global__ void k_gather(const int* __restrict__ eids, const int* __restrict__ map,
                         const float* __restrict__ ent, float* __restrict__ out) {
    int pos = blockIdx.x;                  // 1024 blocks of HID threads
    int u = map[eids[pos]];
    out[(size_t)pos * HID + threadIdx.x] = ent[(size_t)u * HID + threadIdx.x];
}

extern "C" void kernel_launch(void* const* d_in, const int* in_sizes, int n_in,
                              void* d_out, int out_size, void* d_ws, size_t ws_size,
                              hipStream_t stream) {
    const float* x     = (const float*)d_in[0];
    const float* bases = (const float*)d_in[1];
    const float* comp  = (const float*)d_in[2];
    const float* root  = (const float*)d_in[3];
    const float* bias  = (const float*)d_in[4];
    const float* w1    = (const float*)d_in[5];
    const float* b1    = (const float*)d_in[6];
    const float* w2    = (const float*)d_in[7];
    const float* b2    = (const float*)d_in[8];
    const float* wp    = (const float*)d_in[9];
    const float* bp    = (const float*)d_in[10];
    const int* eidx    = (const int*)d_in[11];
    const int* srcp    = eidx;
    const int* dstp    = eidx + N_EDGES;
    const int* etype   = (const int*)d_in[12];
    const int* eids    = (const int*)d_in[13];
    float* out = (float*)d_out;

    int* ws = (int*)d_ws;
    int* map            = ws + OFF_MAP;
    unsigned int* bmap  = (unsigned int*)(ws + OFF_BITMAP);
    int* ucnt           = ws + OFF_UCNT;
    int* bkt            = ws + OFF_BKT;
    float* ent          = (float*)(ws + OFF_ENT);

    hipMemsetAsync(map, 0x7F, (size_t)100032 * sizeof(int), stream);

    k_register<<<1, NPOS, 0, stream>>>(eids, map, bmap, ucnt);
    k_count<<<(N_EDGES / 4 + 255) / 256, 256, 0, stream>>>(srcp, dstp, etype, map,
                                                           bmap, ucnt, bkt);
    k_fused2<<<NPOS / 2, 512, 0, stream>>>(eids, ucnt, bkt, x, comp,
                                           bases, root, bias, w1, b1, w2, b2,
                                           wp, bp, ent);
    k_gather<<<NPOS, HID, 0, stream>>>(eids, map, ent, out);
}